// Round 2
// baseline (79.737 us; speedup 1.0000x reference)
//
#include <hip/hip_runtime.h>
#include <math.h>

#define EPS 1e-9f

// ---------------------------------------------------------------------------
// Ordered-pair pure-gather kernel. Wave t = I*96+J (I,J in [0,96)) computes
// the total force ON tile I's bodies FROM tile J's bodies. Lane l owns I-body
// l; loop step m pairs it with J-body m, where all 64 lanes read the SAME
// LDS address (hardware broadcast, conflict-free, no cross-lane ops).
// No __shfl rotation chain (R1 post-mortem: the loop-carried ds_bpermute
// dependency was the suspected per-wave latency wall), no atomics.
// Each wave writes one private ws[I][J][lane] slot; reduce_ws sums over J.
// Pair math is computed once per DIRECTION (twice per unordered pair), using
// the exact formulas/orientations verified in the R11 rotation kernel.
// ---------------------------------------------------------------------------
__global__ __launch_bounds__(256)
void collide_gather(const float2* __restrict__ cpos,
                    const float*  __restrict__ crad,
                    const float2* __restrict__ apos,
                    const float2* __restrict__ ahalf,
                    float2* __restrict__ ws,
                    int Nc) {
    const int lane = threadIdx.x & 63;
    const int w    = threadIdx.x >> 6;
    const int t    = blockIdx.x * 4 + w;          // ordered pair id 0..9215
    const int I    = t / 96;                      // uniform
    const int J    = t - I * 96;                  // uniform

    const int tileC = Nc >> 6;                    // 64 circle tiles
    const bool IC = I < tileC;                    // uniform
    const bool JC = J < tileC;                    // uniform

    __shared__ float4 Jd[4][128];

    {   // stage J tile (doubled for the diagonal's lane+k gather);
        // circle radius pre-halved
        const int j = (J << 6) + lane;
        float4 q;
        if (JC) {
            const float2 c = cpos[j];
            q = make_float4(c.x, c.y, 0.5f * crad[j], 0.0f);
        } else {
            const float2 a = apos[j - Nc];
            const float2 h = ahalf[j - Nc];
            q = make_float4(a.x, a.y, h.x, h.y);
        }
        Jd[w][lane]      = q;
        Jd[w][lane + 64] = q;
    }
    __syncthreads();

    const int i = (I << 6) + lane;
    float4 me;
    if (IC) {
        const float2 c = cpos[i];
        me = make_float4(c.x, c.y, 0.5f * crad[i], 0.0f);
    } else {
        const float2 a = apos[i - Nc];
        const float2 h = ahalf[i - Nc];
        me = make_float4(a.x, a.y, h.x, h.y);
    }

    float ax = 0.0f, ay = 0.0f;

    if (I != J) {
        if (IC && JC) {                           // CC: circles vs circles
            const float px = me.x, py = me.y, rih = me.z;
            #pragma unroll 8
            for (int m = 0; m < 64; ++m) {
                const float4 q = Jd[w][m];        // broadcast read
                const float dx = px - q.x, dy = py - q.y;        // p - q
                const float d2 = fmaf(dx, dx, dy * dy);
                const float r  = __builtin_amdgcn_rsqf(d2);
                const float s  = fmaxf(fmaf(rih + q.z, r, -0.5f), 0.0f);
                ax = fmaf(s, dx, ax); ay = fmaf(s, dy, ay);
            }
        } else if (IC) {                          // CB: me circle, J boxes
            const float px = me.x, py = me.y, rih = me.z;
            #pragma unroll 8
            for (int m = 0; m < 64; ++m) {
                const float4 q = Jd[w][m];
                const float relx = px - q.x, rely = py - q.y;    // circle - box
                const float cx = fminf(fmaxf(relx, -q.z), q.z);
                const float cy = fminf(fmaxf(rely, -q.w), q.w);
                const float dx = relx - cx, dy = rely - cy;      // = ref diff
                const float d2 = fmaf(dx, dx, dy * dy);
                const float r  = __builtin_amdgcn_rsqf(d2);
                float s = fmaxf(fmaf(rih, r, -0.5f), 0.0f);
                s = (d2 > EPS) ? s : 0.0f;                       // inside-box guard
                ax = fmaf(s, dx, ax); ay = fmaf(s, dy, ay);      // push on circle
            }
        } else if (JC) {                          // BC: me box, J circles
            const float bx = me.x, by = me.y, hx = me.z, hy = me.w;
            #pragma unroll 8
            for (int m = 0; m < 64; ++m) {
                const float4 q = Jd[w][m];
                const float relx = q.x - bx, rely = q.y - by;    // circle - box
                const float cx = fminf(fmaxf(relx, -hx), hx);
                const float cy = fminf(fmaxf(rely, -hy), hy);
                const float dx = relx - cx, dy = rely - cy;
                const float d2 = fmaf(dx, dx, dy * dy);
                const float r  = __builtin_amdgcn_rsqf(d2);
                float s = fmaxf(fmaf(q.z, r, -0.5f), 0.0f);      // q.z = 0.5*rad
                s = (d2 > EPS) ? s : 0.0f;
                ax = fmaf(-s, dx, ax); ay = fmaf(-s, dy, ay);    // opposite on box
            }
        } else {                                  // BB: boxes vs boxes
            const float bx = me.x, by = me.y, hx = me.z, hy = me.w;
            #pragma unroll 8
            for (int m = 0; m < 64; ++m) {
                const float4 q = Jd[w][m];
                const float dax = bx - q.x, day = by - q.y;      // me - q
                const float ovx = (hx + q.z) - fabsf(dax);
                const float ovy = (hy + q.w) - fabsf(day);
                const bool hit = fminf(ovx, ovy) > 0.0f;
                const bool ux  = ovx <= ovy;
                ax += (hit && ux)  ? copysignf(0.5f * ovx, dax) : 0.0f;
                ay += (hit && !ux) ? copysignf(0.5f * ovy, day) : 0.0f;
            }
        }
    } else {
        // diagonal: gather k=1..63 (never self-pairs); fold base position
        // here (each body is in exactly one diag tile). Verbatim verified code.
        if (IC) {                                 // CC diag
            const float px = me.x, py = me.y, rih = me.z;
            #pragma unroll 7
            for (int k = 1; k < 64; ++k) {
                const float4 q = Jd[w][lane + k];
                const float dx = px - q.x, dy = py - q.y;        // p - q
                const float d2 = fmaf(dx, dx, dy * dy);
                const float r  = __builtin_amdgcn_rsqf(d2);
                const float s  = fmaxf(fmaf(rih + q.z, r, -0.5f), 0.0f);
                ax = fmaf(s, dx, ax); ay = fmaf(s, dy, ay);
            }
        } else {                                  // BB diag
            const float bx = me.x, by = me.y, hx = me.z, hy = me.w;
            #pragma unroll 7
            for (int k = 1; k < 64; ++k) {
                const float4 q = Jd[w][lane + k];
                const float dax = bx - q.x, day = by - q.y;
                const float ovx = (hx + q.z) - fabsf(dax);
                const float ovy = (hy + q.w) - fabsf(day);
                const bool hit = fminf(ovx, ovy) > 0.0f;
                const bool ux  = ovx <= ovy;
                ax += (hit && ux)  ? copysignf(0.5f * ovx, dax) : 0.0f;
                ay += (hit && !ux) ? copysignf(0.5f * ovy, day) : 0.0f;
            }
        }
        ax += me.x; ay += me.y;                   // base position
    }

    // private slot, written exactly once
    ws[(I * 96 + J) * 64 + lane] = make_float2(ax, ay);
}

// ---------------------------------------------------------------------------
// Reduce: out[T*64+l] = sum_J ws[T][J][l]. 96 blocks x 1 wave; per-J load is
// 64 consecutive float2 = 512 B coalesced. Deterministic summation order.
// ---------------------------------------------------------------------------
__global__ __launch_bounds__(64)
void reduce_ws(const float2* __restrict__ ws, float2* __restrict__ out) {
    const int T = blockIdx.x;                     // 0..95
    const int l = threadIdx.x;                    // 0..63
    const float2* row = ws + (size_t)(T * 96) * 64 + l;
    float sx = 0.0f, sy = 0.0f;
    #pragma unroll 8
    for (int P = 0; P < 96; ++P) {
        const float2 v = row[(size_t)P * 64];
        sx += v.x; sy += v.y;
    }
    out[(T << 6) + l] = make_float2(sx, sy);
}

// ---------------------------------------------------------------------------
// Fallback: original verified atomic-scatter kernel (only if d_ws too small).
// ---------------------------------------------------------------------------
__device__ __forceinline__ int tri_off(int I) { return I * (193 - I) / 2; }

__global__ __launch_bounds__(256)
void collide_atomic(const float2* __restrict__ cpos,
                    const float*  __restrict__ crad,
                    const float2* __restrict__ apos,
                    const float2* __restrict__ ahalf,
                    float* __restrict__ out,
                    int Nc) {
    const int lane = threadIdx.x & 63;
    const int w    = threadIdx.x >> 6;
    const int t    = blockIdx.x * 4 + w;

    int I = (int)((193.0f - sqrtf((float)(37249 - 8 * t))) * 0.5f);
    while (tri_off(I + 1) <= t) ++I;
    while (tri_off(I) > t) --I;
    const int J = I + (t - tri_off(I));

    const int tileC  = Nc >> 6;
    const bool bodyC = I < tileC;
    const bool partC = J < tileC;

    __shared__ float4 Jd[4][128];

    {
        const int j = (J << 6) + lane;
        float4 q;
        if (partC) {
            const float2 c = cpos[j];
            q = make_float4(c.x, c.y, 0.5f * crad[j], 0.0f);
        } else {
            const float2 a = apos[j - Nc];
            const float2 h = ahalf[j - Nc];
            q = make_float4(a.x, a.y, h.x, h.y);
        }
        Jd[w][lane]      = q;
        Jd[w][lane + 64] = q;
    }
    __syncthreads();

    const int i = (I << 6) + lane;
    float4 me;
    if (bodyC) {
        const float2 c = cpos[i];
        me = make_float4(c.x, c.y, 0.5f * crad[i], 0.0f);
    } else {
        const float2 a = apos[i - Nc];
        const float2 h = ahalf[i - Nc];
        me = make_float4(a.x, a.y, h.x, h.y);
    }

    float ax = 0.0f, ay = 0.0f;
    const int src = (lane + 1) & 63;

    if (I != J) {
        float gx = 0.0f, gy = 0.0f;
        if (partC) {
            const float px = me.x, py = me.y, rih = me.z;
            #pragma unroll 4
            for (int m = 0; m < 64; ++m) {
                const float4 q = Jd[w][lane + m];
                const float dx = q.x - px, dy = q.y - py;
                const float d2 = fmaf(dx, dx, dy * dy);
                const float r  = __builtin_amdgcn_rsqf(d2);
                const float s  = fmaxf(fmaf(rih + q.z, r, -0.5f), 0.0f);
                const float fx = s * dx, fy = s * dy;
                ax -= fx; ay -= fy;
                gx += fx; gy += fy;
                gx = __shfl(gx, src, 64);
                gy = __shfl(gy, src, 64);
            }
        } else if (bodyC) {
            const float px = me.x, py = me.y, rih = me.z;
            #pragma unroll 4
            for (int m = 0; m < 64; ++m) {
                const float4 q = Jd[w][lane + m];
                const float rx = q.x - px, ry = q.y - py;
                const float cx = fminf(fmaxf(rx, -q.z), q.z);
                const float cy = fminf(fmaxf(ry, -q.w), q.w);
                const float dx = rx - cx, dy = ry - cy;
                const float d2 = fmaf(dx, dx, dy * dy);
                const float r  = __builtin_amdgcn_rsqf(d2);
                float s = fmaxf(fmaf(rih, r, -0.5f), 0.0f);
                s = (d2 > EPS) ? s : 0.0f;
                const float fx = s * dx, fy = s * dy;
                ax -= fx; ay -= fy;
                gx += fx; gy += fy;
                gx = __shfl(gx, src, 64);
                gy = __shfl(gy, src, 64);
            }
        } else {
            const float bx = me.x, by = me.y, hx = me.z, hy = me.w;
            #pragma unroll 4
            for (int m = 0; m < 64; ++m) {
                const float4 q = Jd[w][lane + m];
                const float dqx = q.x - bx, dqy = q.y - by;
                const float ovx = (hx + q.z) - fabsf(dqx);
                const float ovy = (hy + q.w) - fabsf(dqy);
                const bool hit = fminf(ovx, ovy) > 0.0f;
                const bool ux  = ovx <= ovy;
                const float fx = (hit && ux)  ? copysignf(0.5f * ovx, dqx) : 0.0f;
                const float fy = (hit && !ux) ? copysignf(0.5f * ovy, dqy) : 0.0f;
                ax -= fx; ay -= fy;
                gx += fx; gy += fy;
                gx = __shfl(gx, src, 64);
                gy = __shfl(gy, src, 64);
            }
        }
        atomicAdd(&out[(((J << 6) + lane) << 1)],     gx);
        atomicAdd(&out[(((J << 6) + lane) << 1) + 1], gy);
    } else {
        if (bodyC) {
            const float px = me.x, py = me.y, rih = me.z;
            #pragma unroll 7
            for (int k = 1; k < 64; ++k) {
                const float4 q = Jd[w][lane + k];
                const float dx = px - q.x, dy = py - q.y;
                const float d2 = fmaf(dx, dx, dy * dy);
                const float r  = __builtin_amdgcn_rsqf(d2);
                const float s  = fmaxf(fmaf(rih + q.z, r, -0.5f), 0.0f);
                ax = fmaf(s, dx, ax); ay = fmaf(s, dy, ay);
            }
        } else {
            const float bx = me.x, by = me.y, hx = me.z, hy = me.w;
            #pragma unroll 7
            for (int k = 1; k < 64; ++k) {
                const float4 q = Jd[w][lane + k];
                const float dax = bx - q.x, day = by - q.y;
                const float ovx = (hx + q.z) - fabsf(dax);
                const float ovy = (hy + q.w) - fabsf(day);
                const bool hit = fminf(ovx, ovy) > 0.0f;
                const bool ux  = ovx <= ovy;
                ax += (hit && ux)  ? copysignf(0.5f * ovx, dax) : 0.0f;
                ay += (hit && !ux) ? copysignf(0.5f * ovy, day) : 0.0f;
            }
        }
        ax += me.x; ay += me.y;
    }

    atomicAdd(&out[(i << 1)],     ax);
    atomicAdd(&out[(i << 1) + 1], ay);
}

extern "C" void kernel_launch(void* const* d_in, const int* in_sizes, int n_in,
                              void* d_out, int out_size, void* d_ws, size_t ws_size,
                              hipStream_t stream) {
    (void)n_in;

    const float2* cpos  = (const float2*)d_in[0];
    const float*  crad  = (const float*) d_in[1];
    const float2* apos  = (const float2*)d_in[2];
    const float2* ahalf = (const float2*)d_in[3];

    const int Nc = in_sizes[1];                 // 4096

    const size_t ws_need = (size_t)96 * 96 * 64 * sizeof(float2);   // 4.72 MB

    if (d_ws != nullptr && ws_size >= ws_need) {
        // ordered-pair pure-gather path: no shfl chain, no atomics
        const int blocks = (96 * 96) / 4;       // 2304
        float2* ws = (float2*)d_ws;
        collide_gather<<<blocks, 256, 0, stream>>>(cpos, crad, apos, ahalf, ws, Nc);
        reduce_ws<<<96, 64, 0, stream>>>(ws, (float2*)d_out);
    } else {
        // fallback: original atomic-scatter path
        hipMemsetAsync(d_out, 0, (size_t)out_size * sizeof(float), stream);
        const int blocks = ((96 * 97) / 2) / 4; // 1164
        collide_atomic<<<blocks, 256, 0, stream>>>(cpos, crad, apos, ahalf,
                                                   (float*)d_out, Nc);
    }
}

// Round 3
// 78.752 us; speedup vs baseline: 1.0125x; 1.0125x over previous
//
#include <hip/hip_runtime.h>
#include <math.h>

#define EPS 1e-9f

__device__ __forceinline__ int tri_off(int I) { return I * (193 - I) / 2; }  // 96 tiles

// ---------------------------------------------------------------------------
// FINAL (revert to R1 variant — best deterministic structure).
//
// Session conclusion: dur_us is pinned at ~77 µs by the harness's 256-MiB
// workspace poison fills, which run at 6.6-6.7 TB/s = 83% of HBM peak (the
// achievable memory roofline). Three structurally radical collide variants
// (atomic scatter / private-slot scatter / pure gather) all landed within
// 2.5 µs — the collide kernel itself contributes only a few µs and is hidden
// under the harness floor.
//
// Main pass: symmetric tile-pair kernel, register-rotation scatter.
// Wave t handles unordered tile pair (I<=J) of 96 body tiles (64 bodies
// each; tiles 0..63 circles, 64..95 boxes). Lane l owns I-body l. J tile
// staged doubled in per-wave LDS (stride-1 ds_read_b128, conflict-free).
// Off-diagonal: at step m lane l computes pair (I-body l, J-body (l+m)&63),
// computes the force ON the J body, adds it to a rotating register
// accumulator g, then rotates g one lane. After 64 add+rotate steps lane l
// holds J-body l's total. I side accumulates -f. Diagonal: pure gather
// k=1..63 + base-position fold. Output: private written-exactly-once
// workspace slots ws[(T*96+P)*64+lane] + deterministic reduce. No atomics.
// ---------------------------------------------------------------------------
__global__ __launch_bounds__(256)
void collide_ws(const float2* __restrict__ cpos,
                const float*  __restrict__ crad,
                const float2* __restrict__ apos,
                const float2* __restrict__ ahalf,
                float2* __restrict__ ws,
                int Nc) {
    const int lane = threadIdx.x & 63;
    const int w    = threadIdx.x >> 6;
    const int t    = blockIdx.x * 4 + w;          // tile-pair id 0..4655 (uniform)

    // triangular decode t -> (I, J), I <= J  (37249 - 8t exact in f32)
    int I = (int)((193.0f - sqrtf((float)(37249 - 8 * t))) * 0.5f);
    while (tri_off(I + 1) <= t) ++I;
    while (tri_off(I) > t) --I;
    const int J = I + (t - tri_off(I));

    const int tileC  = Nc >> 6;                   // 64 circle tiles
    const bool bodyC = I < tileC;                 // uniform
    const bool partC = J < tileC;                 // uniform (I<=J: partC => bodyC)

    __shared__ float4 Jd[4][128];

    {   // stage J tile (doubled) straight from inputs; circle radius pre-halved
        const int j = (J << 6) + lane;
        float4 q;
        if (partC) {
            const float2 c = cpos[j];
            q = make_float4(c.x, c.y, 0.5f * crad[j], 0.0f);
        } else {
            const float2 a = apos[j - Nc];
            const float2 h = ahalf[j - Nc];
            q = make_float4(a.x, a.y, h.x, h.y);
        }
        Jd[w][lane]      = q;
        Jd[w][lane + 64] = q;
    }
    __syncthreads();

    const int i = (I << 6) + lane;
    float4 me;
    if (bodyC) {
        const float2 c = cpos[i];
        me = make_float4(c.x, c.y, 0.5f * crad[i], 0.0f);
    } else {
        const float2 a = apos[i - Nc];
        const float2 h = ahalf[i - Nc];
        me = make_float4(a.x, a.y, h.x, h.y);
    }

    float ax = 0.0f, ay = 0.0f;
    const int src = (lane + 1) & 63;              // rotation source lane

    if (I != J) {
        float gx = 0.0f, gy = 0.0f;               // rotating J-side accumulator
        if (partC) {                              // CC (both circle tiles)
            const float px = me.x, py = me.y, rih = me.z;
            #pragma unroll 4
            for (int m = 0; m < 64; ++m) {
                const float4 q = Jd[w][lane + m];
                const float dx = q.x - px, dy = q.y - py;        // q - p
                const float d2 = fmaf(dx, dx, dy * dy);
                const float r  = __builtin_amdgcn_rsqf(d2);
                const float s  = fmaxf(fmaf(rih + q.z, r, -0.5f), 0.0f);
                const float fx = s * dx, fy = s * dy;            // force on J body
                ax -= fx; ay -= fy;                              // equal & opposite on I
                gx += fx; gy += fy;
                gx = __shfl(gx, src, 64);                        // rotate accumulator
                gy = __shfl(gy, src, 64);
            }
        } else if (bodyC) {                       // CB: I circle tile, J box tile
            const float px = me.x, py = me.y, rih = me.z;
            #pragma unroll 4
            for (int m = 0; m < 64; ++m) {
                const float4 q = Jd[w][lane + m];
                const float rx = q.x - px, ry = q.y - py;        // box - circle
                const float cx = fminf(fmaxf(rx, -q.z), q.z);
                const float cy = fminf(fmaxf(ry, -q.w), q.w);
                const float dx = rx - cx, dy = ry - cy;          // = -(ref diff)
                const float d2 = fmaf(dx, dx, dy * dy);
                const float r  = __builtin_amdgcn_rsqf(d2);
                float s = fmaxf(fmaf(rih, r, -0.5f), 0.0f);
                s = (d2 > EPS) ? s : 0.0f;                       // center-inside-box guard
                const float fx = s * dx, fy = s * dy;            // force on box
                ax -= fx; ay -= fy;                              // push on circle
                gx += fx; gy += fy;
                gx = __shfl(gx, src, 64);
                gy = __shfl(gy, src, 64);
            }
        } else {                                  // BB (both box tiles)
            const float bx = me.x, by = me.y, hx = me.z, hy = me.w;
            #pragma unroll 4
            for (int m = 0; m < 64; ++m) {
                const float4 q = Jd[w][lane + m];
                const float dqx = q.x - bx, dqy = q.y - by;      // q - me
                const float ovx = (hx + q.z) - fabsf(dqx);
                const float ovy = (hy + q.w) - fabsf(dqy);
                const bool hit = fminf(ovx, ovy) > 0.0f;
                const bool ux  = ovx <= ovy;
                const float fx = (hit && ux)  ? copysignf(0.5f * ovx, dqx) : 0.0f;
                const float fy = (hit && !ux) ? copysignf(0.5f * ovy, dqy) : 0.0f;
                ax -= fx; ay -= fy;
                gx += fx; gy += fy;
                gx = __shfl(gx, src, 64);
                gy = __shfl(gy, src, 64);
            }
        }
        // J-side partial: slot [J][I][lane], written exactly once
        ws[(J * 96 + I) * 64 + lane] = make_float2(gx, gy);
    } else {
        // diagonal: gather k=1..63; fold base position here (unique per body)
        if (bodyC) {                              // CC diag
            const float px = me.x, py = me.y, rih = me.z;
            #pragma unroll 7
            for (int k = 1; k < 64; ++k) {
                const float4 q = Jd[w][lane + k];
                const float dx = px - q.x, dy = py - q.y;        // p - q (I side)
                const float d2 = fmaf(dx, dx, dy * dy);
                const float r  = __builtin_amdgcn_rsqf(d2);
                const float s  = fmaxf(fmaf(rih + q.z, r, -0.5f), 0.0f);
                ax = fmaf(s, dx, ax); ay = fmaf(s, dy, ay);
            }
        } else {                                  // BB diag
            const float bx = me.x, by = me.y, hx = me.z, hy = me.w;
            #pragma unroll 7
            for (int k = 1; k < 64; ++k) {
                const float4 q = Jd[w][lane + k];
                const float dax = bx - q.x, day = by - q.y;
                const float ovx = (hx + q.z) - fabsf(dax);
                const float ovy = (hy + q.w) - fabsf(day);
                const bool hit = fminf(ovx, ovy) > 0.0f;
                const bool ux  = ovx <= ovy;
                ax += (hit && ux)  ? copysignf(0.5f * ovx, dax) : 0.0f;
                ay += (hit && !ux) ? copysignf(0.5f * ovy, day) : 0.0f;
            }
        }
        ax += me.x; ay += me.y;                   // base position
    }

    // I-side partial (diag: the [I][I] slot): written exactly once
    ws[(I * 96 + J) * 64 + lane] = make_float2(ax, ay);
}

// ---------------------------------------------------------------------------
// Reduce: out[T*64+l] = sum_P ws[T][P][l]. 96 blocks x 1 wave; per-P load is
// 64 consecutive float2 = 512 B coalesced. Reads 4.7 MB total, writes out
// exactly once (no memset needed). Deterministic summation order.
// ---------------------------------------------------------------------------
__global__ __launch_bounds__(64)
void reduce_ws(const float2* __restrict__ ws, float2* __restrict__ out) {
    const int T = blockIdx.x;                     // 0..95
    const int l = threadIdx.x;                    // 0..63
    const float2* row = ws + (size_t)(T * 96) * 64 + l;
    float sx = 0.0f, sy = 0.0f;
    #pragma unroll 8
    for (int P = 0; P < 96; ++P) {
        const float2 v = row[(size_t)P * 64];
        sx += v.x; sy += v.y;
    }
    out[(T << 6) + l] = make_float2(sx, sy);
}

// ---------------------------------------------------------------------------
// Fallback: original verified atomic-scatter kernel (used only if d_ws is
// unexpectedly too small for the 4.72 MB partial buffer).
// ---------------------------------------------------------------------------
__global__ __launch_bounds__(256)
void collide_atomic(const float2* __restrict__ cpos,
                    const float*  __restrict__ crad,
                    const float2* __restrict__ apos,
                    const float2* __restrict__ ahalf,
                    float* __restrict__ out,
                    int Nc) {
    const int lane = threadIdx.x & 63;
    const int w    = threadIdx.x >> 6;
    const int t    = blockIdx.x * 4 + w;

    int I = (int)((193.0f - sqrtf((float)(37249 - 8 * t))) * 0.5f);
    while (tri_off(I + 1) <= t) ++I;
    while (tri_off(I) > t) --I;
    const int J = I + (t - tri_off(I));

    const int tileC  = Nc >> 6;
    const bool bodyC = I < tileC;
    const bool partC = J < tileC;

    __shared__ float4 Jd[4][128];

    {
        const int j = (J << 6) + lane;
        float4 q;
        if (partC) {
            const float2 c = cpos[j];
            q = make_float4(c.x, c.y, 0.5f * crad[j], 0.0f);
        } else {
            const float2 a = apos[j - Nc];
            const float2 h = ahalf[j - Nc];
            q = make_float4(a.x, a.y, h.x, h.y);
        }
        Jd[w][lane]      = q;
        Jd[w][lane + 64] = q;
    }
    __syncthreads();

    const int i = (I << 6) + lane;
    float4 me;
    if (bodyC) {
        const float2 c = cpos[i];
        me = make_float4(c.x, c.y, 0.5f * crad[i], 0.0f);
    } else {
        const float2 a = apos[i - Nc];
        const float2 h = ahalf[i - Nc];
        me = make_float4(a.x, a.y, h.x, h.y);
    }

    float ax = 0.0f, ay = 0.0f;
    const int src = (lane + 1) & 63;

    if (I != J) {
        float gx = 0.0f, gy = 0.0f;
        if (partC) {
            const float px = me.x, py = me.y, rih = me.z;
            #pragma unroll 4
            for (int m = 0; m < 64; ++m) {
                const float4 q = Jd[w][lane + m];
                const float dx = q.x - px, dy = q.y - py;
                const float d2 = fmaf(dx, dx, dy * dy);
                const float r  = __builtin_amdgcn_rsqf(d2);
                const float s  = fmaxf(fmaf(rih + q.z, r, -0.5f), 0.0f);
                const float fx = s * dx, fy = s * dy;
                ax -= fx; ay -= fy;
                gx += fx; gy += fy;
                gx = __shfl(gx, src, 64);
                gy = __shfl(gy, src, 64);
            }
        } else if (bodyC) {
            const float px = me.x, py = me.y, rih = me.z;
            #pragma unroll 4
            for (int m = 0; m < 64; ++m) {
                const float4 q = Jd[w][lane + m];
                const float rx = q.x - px, ry = q.y - py;
                const float cx = fminf(fmaxf(rx, -q.z), q.z);
                const float cy = fminf(fmaxf(ry, -q.w), q.w);
                const float dx = rx - cx, dy = ry - cy;
                const float d2 = fmaf(dx, dx, dy * dy);
                const float r  = __builtin_amdgcn_rsqf(d2);
                float s = fmaxf(fmaf(rih, r, -0.5f), 0.0f);
                s = (d2 > EPS) ? s : 0.0f;
                const float fx = s * dx, fy = s * dy;
                ax -= fx; ay -= fy;
                gx += fx; gy += fy;
                gx = __shfl(gx, src, 64);
                gy = __shfl(gy, src, 64);
            }
        } else {
            const float bx = me.x, by = me.y, hx = me.z, hy = me.w;
            #pragma unroll 4
            for (int m = 0; m < 64; ++m) {
                const float4 q = Jd[w][lane + m];
                const float dqx = q.x - bx, dqy = q.y - by;
                const float ovx = (hx + q.z) - fabsf(dqx);
                const float ovy = (hy + q.w) - fabsf(dqy);
                const bool hit = fminf(ovx, ovy) > 0.0f;
                const bool ux  = ovx <= ovy;
                const float fx = (hit && ux)  ? copysignf(0.5f * ovx, dqx) : 0.0f;
                const float fy = (hit && !ux) ? copysignf(0.5f * ovy, dqy) : 0.0f;
                ax -= fx; ay -= fy;
                gx += fx; gy += fy;
                gx = __shfl(gx, src, 64);
                gy = __shfl(gy, src, 64);
            }
        }
        atomicAdd(&out[(((J << 6) + lane) << 1)],     gx);
        atomicAdd(&out[(((J << 6) + lane) << 1) + 1], gy);
    } else {
        if (bodyC) {
            const float px = me.x, py = me.y, rih = me.z;
            #pragma unroll 7
            for (int k = 1; k < 64; ++k) {
                const float4 q = Jd[w][lane + k];
                const float dx = px - q.x, dy = py - q.y;
                const float d2 = fmaf(dx, dx, dy * dy);
                const float r  = __builtin_amdgcn_rsqf(d2);
                const float s  = fmaxf(fmaf(rih + q.z, r, -0.5f), 0.0f);
                ax = fmaf(s, dx, ax); ay = fmaf(s, dy, ay);
            }
        } else {
            const float bx = me.x, by = me.y, hx = me.z, hy = me.w;
            #pragma unroll 7
            for (int k = 1; k < 64; ++k) {
                const float4 q = Jd[w][lane + k];
                const float dax = bx - q.x, day = by - q.y;
                const float ovx = (hx + q.z) - fabsf(dax);
                const float ovy = (hy + q.w) - fabsf(day);
                const bool hit = fminf(ovx, ovy) > 0.0f;
                const bool ux  = ovx <= ovy;
                ax += (hit && ux)  ? copysignf(0.5f * ovx, dax) : 0.0f;
                ay += (hit && !ux) ? copysignf(0.5f * ovy, day) : 0.0f;
            }
        }
        ax += me.x; ay += me.y;
    }

    atomicAdd(&out[(i << 1)],     ax);
    atomicAdd(&out[(i << 1) + 1], ay);
}

extern "C" void kernel_launch(void* const* d_in, const int* in_sizes, int n_in,
                              void* d_out, int out_size, void* d_ws, size_t ws_size,
                              hipStream_t stream) {
    (void)n_in;

    const float2* cpos  = (const float2*)d_in[0];
    const float*  crad  = (const float*) d_in[1];
    const float2* apos  = (const float2*)d_in[2];
    const float2* ahalf = (const float2*)d_in[3];

    const int Nc = in_sizes[1];                 // 4096

    const int tile_pairs = (96 * 97) / 2;       // 4656
    const int blocks = tile_pairs / 4;          // 1164

    const size_t ws_need = (size_t)96 * 96 * 64 * sizeof(float2);   // 4.72 MB

    if (d_ws != nullptr && ws_size >= ws_need) {
        // atomic-free path: partials to private slots, then deterministic reduce
        float2* ws = (float2*)d_ws;
        collide_ws<<<blocks, 256, 0, stream>>>(cpos, crad, apos, ahalf, ws, Nc);
        reduce_ws<<<96, 64, 0, stream>>>(ws, (float2*)d_out);
    } else {
        // fallback: original atomic-scatter path
        hipMemsetAsync(d_out, 0, (size_t)out_size * sizeof(float), stream);
        collide_atomic<<<blocks, 256, 0, stream>>>(cpos, crad, apos, ahalf,
                                                   (float*)d_out, Nc);
    }
}